// Round 5
// baseline (609.779 us; speedup 1.0000x reference)
//
#include <hip/hip_runtime.h>
#include <math.h>

#define N_NODES 100000
#define N_EDGES 1600000
#define DIN 128
#define DH 32
#define NEG_SLOPE 0.2f
#define BN_EPS 1e-5f
#define MT 64        // nodes per transform block
#define SCHUNK 512   // node-scan chunk
#define BSHIFT 9     // 512 nodes per bucket
#define NBUCK 196    // ceil(N_NODES / 512)
#define B_SCAT 256   // blocks for bucket hist/scatter
#define CPB ((N_EDGES + B_SCAT - 1) / B_SCAT)

typedef __attribute__((ext_vector_type(8))) short short8;
typedef __attribute__((ext_vector_type(4))) float f32x4;

__device__ __forceinline__ unsigned short f2bf(float f) {
    unsigned int u = __float_as_uint(f);
    u = (u + 0x7FFFu + ((u >> 16) & 1u)) >> 16;
    return (unsigned short)u;
}
__device__ __forceinline__ float bf2f(unsigned short h) {
    return __uint_as_float((unsigned int)h << 16);
}

// ---------------- CSR build: two-level counting sort ----------------
// Phase 1: per-block bucket histograms (+ fused per-node degree histogram)

__global__ __launch_bounds__(256) void bucket_hist_kernel(
    const int* __restrict__ dst, int* __restrict__ deg, int* __restrict__ bh, int e) {
    __shared__ int lh[NBUCK];
    for (int j = threadIdx.x; j < NBUCK; j += 256) lh[j] = 0;
    __syncthreads();
    int b = blockIdx.x;
    int lo = b * CPB, hi = min(lo + CPB, e);
    for (int i = lo + threadIdx.x; i < hi; i += 256) {
        int d = dst[i];
        atomicAdd(&deg[d], 1);
        atomicAdd(&lh[d >> BSHIFT], 1);
    }
    __syncthreads();
    for (int j = threadIdx.x; j < NBUCK; j += 256) bh[j * B_SCAT + b] = lh[j];
}

// Phase 2: exclusive scan over NBUCK*B_SCAT counters (bucket-major)
__global__ __launch_bounds__(1024) void bucket_scan_kernel(
    const int* __restrict__ bh, int* __restrict__ bs, int total) {
    __shared__ int part[1024];
    int t = threadIdx.x;
    int chunk = (total + 1023) >> 10;
    int lo = t * chunk, hi = min(lo + chunk, total);
    int s = 0;
    for (int i = lo; i < hi; ++i) s += bh[i];
    part[t] = s;
    __syncthreads();
    for (int d = 1; d < 1024; d <<= 1) {
        int v = (t >= d) ? part[t - d] : 0;
        __syncthreads();
        part[t] += v;
        __syncthreads();
    }
    int run = t ? part[t - 1] : 0;
    for (int i = lo; i < hi; ++i) { int v = bh[i]; bs[i] = run; run += v; }
}

// Phase 3: bucketed scatter; each (block,bucket) region is private+contiguous
__global__ __launch_bounds__(256) void bucket_scatter_kernel(
    const int* __restrict__ src, const int* __restrict__ dst, const int* __restrict__ et,
    const int* __restrict__ bs, int2* __restrict__ rec, int e) {
    __shared__ int cur[NBUCK];
    int b = blockIdx.x;
    for (int j = threadIdx.x; j < NBUCK; j += 256) cur[j] = bs[j * B_SCAT + b];
    __syncthreads();
    int lo = b * CPB, hi = min(lo + CPB, e);
    for (int i = lo + threadIdx.x; i < hi; i += 256) {
        int d = dst[i];
        int pos = atomicAdd(&cur[d >> BSHIFT], 1);
        rec[pos] = make_int2(d, src[i] | (et[i] << 30));
    }
}

// Phase 4: fine scatter within each bucket (output window ~32KB, LDS cursors)
__global__ __launch_bounds__(256) void fine_scatter_kernel(
    const int2* __restrict__ rec, const int* __restrict__ bs, const int* __restrict__ off,
    int* __restrict__ packed, int n, int e) {
    __shared__ int lcur[1 << BSHIFT];
    int k = blockIdx.x;
    int nb0 = k << BSHIFT;
    for (int j = threadIdx.x; j < (1 << BSHIFT); j += 256) {
        int node = nb0 + j;
        lcur[j] = (node < n) ? off[node] : 0;
    }
    __syncthreads();
    int start = bs[k * B_SCAT];
    int end = (k + 1 < NBUCK) ? bs[(k + 1) * B_SCAT] : e;
    for (int i = start + threadIdx.x; i < end; i += 256) {
        int2 r = rec[i];
        int pos = atomicAdd(&lcur[r.x - nb0], 1);
        packed[pos] = r.y;
    }
}

// ---------------- node-degree scan (two-level) ----------------

__global__ __launch_bounds__(256) void scan_part_kernel(
    const int* __restrict__ deg, int* __restrict__ partials, int n) {
    __shared__ int sdata[256];
    int b = blockIdx.x, t = threadIdx.x;
    int i0 = b * SCHUNK + t;
    int s = 0;
    if (i0 < n) s += deg[i0];
    if (i0 + 256 < n && t + 256 < SCHUNK) s += deg[i0 + 256];
    sdata[t] = s;
    __syncthreads();
    for (int d = 128; d; d >>= 1) {
        if (t < d) sdata[t] += sdata[t + d];
        __syncthreads();
    }
    if (t == 0) partials[b] = sdata[0];
}

__global__ __launch_bounds__(1024) void scan_top_kernel(int* __restrict__ partials, int nb) {
    __shared__ int sdata[1024];
    int t = threadIdx.x;
    sdata[t] = (t < nb) ? partials[t] : 0;
    __syncthreads();
    for (int d = 1; d < 1024; d <<= 1) {
        int v = (t >= d) ? sdata[t - d] : 0;
        __syncthreads();
        sdata[t] += v;
        __syncthreads();
    }
    if (t < nb) partials[t] = (t == 0) ? 0 : sdata[t - 1];
}

__global__ __launch_bounds__(SCHUNK) void scan_final_kernel(
    const int* __restrict__ deg, const int* __restrict__ partials,
    int* __restrict__ off, int n, int e) {
    __shared__ int sdata[SCHUNK];
    int b = blockIdx.x, t = threadIdx.x;
    int i = b * SCHUNK + t;
    sdata[t] = (i < n) ? deg[i] : 0;
    __syncthreads();
    for (int d = 1; d < SCHUNK; d <<= 1) {
        int v = (t >= d) ? sdata[t - d] : 0;
        __syncthreads();
        sdata[t] += v;
        __syncthreads();
    }
    int excl = (t == 0) ? 0 : sdata[t - 1];
    if (i < n) off[i] = partials[b] + excl;
    if (b == 0 && t == 0) off[n] = e;
}

// -------- weight conversion: Wt[col][k] = split-bf16 of w[r][k][c], col=r*32+c ----

__global__ void wconv_kernel(const float* __restrict__ w,
                             unsigned short* __restrict__ wt_hi,
                             unsigned short* __restrict__ wt_lo, int K) {
    int i = blockIdx.x * blockDim.x + threadIdx.x;
    if (i >= 64 * K) return;
    int col = i / K, k = i % K;
    int r = col >> 5, c = col & 31;
    float v = w[(r * K + k) * DH + c];
    unsigned short h = f2bf(v);
    wt_hi[i] = h;
    wt_lo[i] = f2bf(v - bf2f(h));
}

// ---------------- MFMA transform: y[node][64] = X[node][K] @ Wmat[K][64] ----------
// Split-bf16 (hi+lo) on both operands: acc = aH*bH + aH*bL + aL*bH  (~fp32 accuracy).
// Fuses previous layer's BN into staging (FUSE_BN) and q/k row-dots into epilogue.

template<int K, bool FUSE_BN>
__global__ __launch_bounds__(256) void transform_mfma_kernel(
    const float* __restrict__ xin, const float* __restrict__ stats,
    const float* __restrict__ gamma, const float* __restrict__ beta,
    const unsigned short* __restrict__ WtHi, const unsigned short* __restrict__ WtLo,
    const float* __restrict__ Qw, const float* __restrict__ Kw,
    float* __restrict__ y, float* __restrict__ qv, float* __restrict__ kv, int n) {
    constexpr int LDK = K + 8;          // +8 elems (16B) pad -> bank spread
    constexpr int KT = K / 32;
    __shared__ unsigned short xs_hi[MT * LDK];
    __shared__ unsigned short xs_lo[MT * LDK];
    __shared__ float scs[DH], shs[DH];
    int tid = threadIdx.x;
    int base = blockIdx.x * MT;

    if (FUSE_BN) {
        if (tid < DH) {
            float mu = stats[tid] * (1.f / N_NODES);
            float var = stats[DH + tid] * (1.f / N_NODES) - mu * mu;
            float inv = rsqrtf(var + BN_EPS);
            float sc = gamma[tid] * inv;
            scs[tid] = sc;
            shs[tid] = beta[tid] - mu * sc;
        }
        __syncthreads();
    }

    // stage X tile (fp32 -> hi/lo bf16) into LDS
    constexpr int CH = K / 4;
    for (int c = tid; c < MT * CH; c += 256) {
        int row = c / CH, c4 = c % CH;
        int node = base + row;
        float4 v = make_float4(0.f, 0.f, 0.f, 0.f);
        if (node < n) v = ((const float4*)(xin + (size_t)node * K))[c4];
        if (FUSE_BN) {
            int c0 = c4 * 4;
            v.x = v.x * scs[c0 + 0] + shs[c0 + 0];
            v.y = v.y * scs[c0 + 1] + shs[c0 + 1];
            v.z = v.z * scs[c0 + 2] + shs[c0 + 2];
            v.w = v.w * scs[c0 + 3] + shs[c0 + 3];
        }
        ushort4 hb = make_ushort4(f2bf(v.x), f2bf(v.y), f2bf(v.z), f2bf(v.w));
        ushort4 lb = make_ushort4(f2bf(v.x - bf2f(hb.x)), f2bf(v.y - bf2f(hb.y)),
                                  f2bf(v.z - bf2f(hb.z)), f2bf(v.w - bf2f(hb.w)));
        *(ushort4*)(&xs_hi[row * LDK + c4 * 4]) = hb;
        *(ushort4*)(&xs_lo[row * LDK + c4 * 4]) = lb;
    }
    __syncthreads();

    int lane = tid & 63;
    int wave = tid >> 6;                 // 4 waves x 16 rows
    int r16 = lane & 15, g = lane >> 4;  // frag coords
    int wrow = wave * 16;

    f32x4 acc[4];
#pragma unroll
    for (int nt = 0; nt < 4; ++nt) acc[nt] = f32x4{0.f, 0.f, 0.f, 0.f};

#pragma unroll
    for (int kt = 0; kt < KT; ++kt) {
        short8 a_hi = *(const short8*)(&xs_hi[(wrow + r16) * LDK + kt * 32 + g * 8]);
        short8 a_lo = *(const short8*)(&xs_lo[(wrow + r16) * LDK + kt * 32 + g * 8]);
#pragma unroll
        for (int nt = 0; nt < 4; ++nt) {
            const size_t bo = (size_t)(nt * 16 + r16) * K + kt * 32 + g * 8;
            short8 b_hi = *(const short8*)(WtHi + bo);
            short8 b_lo = *(const short8*)(WtLo + bo);
            acc[nt] = __builtin_amdgcn_mfma_f32_16x16x32_bf16(a_hi, b_hi, acc[nt], 0, 0, 0);
            acc[nt] = __builtin_amdgcn_mfma_f32_16x16x32_bf16(a_hi, b_lo, acc[nt], 0, 0, 0);
            acc[nt] = __builtin_amdgcn_mfma_f32_16x16x32_bf16(a_lo, b_hi, acc[nt], 0, 0, 0);
        }
    }

    // epilogue: y stores + fused q/k row-dots
    float qp[2][4] = {{0.f, 0.f, 0.f, 0.f}, {0.f, 0.f, 0.f, 0.f}};
    float kp[2][4] = {{0.f, 0.f, 0.f, 0.f}, {0.f, 0.f, 0.f, 0.f}};
#pragma unroll
    for (int nt = 0; nt < 4; ++nt) {
        int col = nt * 16 + r16;
        int rr = col >> 5, cc = col & 31;
        float qw = Qw[rr * DH + cc], kw = Kw[rr * DH + cc];
#pragma unroll
        for (int j = 0; j < 4; ++j) {
            float v = acc[nt][j];
            qp[rr][j] += v * qw;
            kp[rr][j] += v * kw;
            int node = base + wrow + g * 4 + j;
            if (node < n) y[(size_t)node * 64 + col] = v;
        }
    }
#pragma unroll
    for (int j = 0; j < 4; ++j) {
#pragma unroll
        for (int rr = 0; rr < 2; ++rr) {
            float q = qp[rr][j], k = kp[rr][j];
            for (int d = 8; d; d >>= 1) {
                q += __shfl_xor(q, d, 16);
                k += __shfl_xor(k, d, 16);
            }
            if (r16 == 0) {
                int node = base + wrow + g * 4 + j;
                if (node < n) {
                    qv[node * 2 + rr] = q;
                    kv[node * 2 + rr] = k;
                }
            }
        }
    }
}

// ---------------- fused attention + aggregate + relu + BN stats ----------------
// Single sweep: normalization applied after aggregation (h = (Σ w·y)/Σ w).
// Per ≤32-edge chunk: each lane computes its edge's weight, then (w,row) are
// broadcast via shfl for the feature-parallel y gather. No ebuf, no second pass.

__global__ __launch_bounds__(256) void attn_kernel(
    const int* __restrict__ off, const int* __restrict__ packed,
    const float* __restrict__ y, const float* __restrict__ qv, const float* __restrict__ kv,
    const float* __restrict__ bias, float* __restrict__ hpre,
    float* __restrict__ stats, int n) {
    __shared__ float ssum[DH], ssq[DH];
    if (threadIdx.x < DH) { ssum[threadIdx.x] = 0.f; ssq[threadIdx.x] = 0.f; }
    __syncthreads();
    int lane = threadIdx.x & 31;
    int sub = threadIdx.x >> 5;
    int spb = blockDim.x >> 5;
    float rsum = 0.f, rsq = 0.f;
    for (int node = blockIdx.x * spb + sub; node < n; node += gridDim.x * spb) {
        int lo = off[node], hi = off[node + 1];
        float q0 = qv[node * 2], q1 = qv[node * 2 + 1];
        float acc = 0.f, wsum = 0.f;
        for (int base = lo; base < hi; base += 32) {
            int i = base + lane;
            float w = 0.f;
            int row = 0;
            if (i < hi) {
                int p = packed[i];
                int s = p & 0x3FFFFFFF, r = p >> 30;
                float e = (r ? q1 : q0) + kv[s * 2 + r];
                e = e > 0.f ? e : NEG_SLOPE * e;
                w = __expf(e - 8.f);
                row = s * 64 + r * 32;
            }
            wsum += w;
            int cnt = min(32, hi - base);
            for (int j = 0; j < cnt; ++j) {
                float wj = __shfl(w, j, 32);
                int rowj = __shfl(row, j, 32);
                acc += wj * y[rowj + lane];
            }
        }
        for (int d = 16; d; d >>= 1) wsum += __shfl_xor(wsum, d, 32);
        float h = fmaxf(acc / (wsum + 1e-16f) + bias[lane], 0.f);
        hpre[(size_t)node * DH + lane] = h;
        rsum += h;
        rsq += h * h;
    }
    atomicAdd(&ssum[lane], rsum);
    atomicAdd(&ssq[lane], rsq);
    __syncthreads();
    if (threadIdx.x < DH) {
        atomicAdd(&stats[threadIdx.x], ssum[threadIdx.x]);
        atomicAdd(&stats[DH + threadIdx.x], ssq[threadIdx.x]);
    }
}

// ---------------- final BN + MLP head ----------------

__global__ __launch_bounds__(256) void mlp_kernel(
    const float* __restrict__ hpre, const float* __restrict__ stats,
    const float* __restrict__ gamma, const float* __restrict__ beta,
    const float* __restrict__ mw1, const float* __restrict__ mb1,
    const float* __restrict__ mw2, const float* __restrict__ mb2,
    float* __restrict__ out, int n) {
    int g = (blockIdx.x * blockDim.x + threadIdx.x) >> 5;
    int lane = threadIdx.x & 31;
    if (g >= n) return;
    float mu = stats[lane] * (1.f / N_NODES);
    float var = stats[DH + lane] * (1.f / N_NODES) - mu * mu;
    float inv = rsqrtf(var + BN_EPS);
    float h = gamma[lane] * (hpre[(size_t)g * DH + lane] - mu) * inv + beta[lane];
    float a = mb1[lane];
#pragma unroll
    for (int f = 0; f < DH; ++f) a += __shfl(h, f, 32) * mw1[f * DH + lane];
    float s = 1.f / (1.f + __expf(-a));
    float o0 = s * mw2[lane * 2 + 0];
    float o1 = s * mw2[lane * 2 + 1];
    for (int d = 16; d; d >>= 1) {
        o0 += __shfl_xor(o0, d, 32);
        o1 += __shfl_xor(o1, d, 32);
    }
    if (lane == 0) {
        out[(size_t)g * 2 + 0] = o0 + mb2[0];
        out[(size_t)g * 2 + 1] = o1 + mb2[1];
    }
}

// ---------------- launch ----------------

extern "C" void kernel_launch(void* const* d_in, const int* in_sizes, int n_in,
                              void* d_out, int out_size, void* d_ws, size_t ws_size,
                              hipStream_t stream) {
    const float* x = (const float*)d_in[0];
    const int* edge_index = (const int*)d_in[1];
    const int* edge_type = (const int*)d_in[2];
    const float* w[3]  = {(const float*)d_in[3],  (const float*)d_in[9],  (const float*)d_in[15]};
    const float* aq[3] = {(const float*)d_in[4],  (const float*)d_in[10], (const float*)d_in[16]};
    const float* ak[3] = {(const float*)d_in[5],  (const float*)d_in[11], (const float*)d_in[17]};
    const float* bb[3] = {(const float*)d_in[6],  (const float*)d_in[12], (const float*)d_in[18]};
    const float* gm[3] = {(const float*)d_in[7],  (const float*)d_in[13], (const float*)d_in[19]};
    const float* be[3] = {(const float*)d_in[8],  (const float*)d_in[14], (const float*)d_in[20]};
    const float* mw1 = (const float*)d_in[21];
    const float* mb1 = (const float*)d_in[22];
    const float* mw2 = (const float*)d_in[23];
    const float* mb2 = (const float*)d_in[24];
    float* out = (float*)d_out;

    const int n = N_NODES, e = N_EDGES;
    char* ws = (char*)d_ws;
    auto alloc = [&](size_t bytes) {
        char* p = ws;
        ws += (bytes + 255) & ~(size_t)255;
        return p;
    };
    int* deg      = (int*)alloc((size_t)n * 4);
    int* off      = (int*)alloc((size_t)(n + 1) * 4);
    int* partials = (int*)alloc((size_t)1024 * 4);
    int* bhist    = (int*)alloc((size_t)NBUCK * B_SCAT * 4);
    int* bscan    = (int*)alloc((size_t)NBUCK * B_SCAT * 4);
    int2* rec     = (int2*)alloc((size_t)e * 8);
    int* packed   = (int*)alloc((size_t)e * 4);
    float* y      = (float*)alloc((size_t)n * 2 * DH * 4);
    float* qv     = (float*)alloc((size_t)n * 2 * 4);
    float* kv     = (float*)alloc((size_t)n * 2 * 4);
    float* hpre   = (float*)alloc((size_t)n * DH * 4);
    float* stats  = (float*)alloc(3 * 2 * DH * 4);
    unsigned short* wt0h = (unsigned short*)alloc((size_t)64 * DIN * 2);
    unsigned short* wt0l = (unsigned short*)alloc((size_t)64 * DIN * 2);
    unsigned short* wt1h = (unsigned short*)alloc((size_t)64 * DH * 2);
    unsigned short* wt1l = (unsigned short*)alloc((size_t)64 * DH * 2);
    unsigned short* wt2h = (unsigned short*)alloc((size_t)64 * DH * 2);
    unsigned short* wt2l = (unsigned short*)alloc((size_t)64 * DH * 2);

    hipMemsetAsync(deg, 0, (size_t)n * 4, stream);
    hipMemsetAsync(stats, 0, 3 * 2 * DH * 4, stream);

    const int* src = edge_index;
    const int* dst = edge_index + e;

    wconv_kernel<<<(64 * DIN + 255) / 256, 256, 0, stream>>>(w[0], wt0h, wt0l, DIN);
    wconv_kernel<<<(64 * DH + 255) / 256, 256, 0, stream>>>(w[1], wt1h, wt1l, DH);
    wconv_kernel<<<(64 * DH + 255) / 256, 256, 0, stream>>>(w[2], wt2h, wt2l, DH);

    // CSR build: bucket hist (+deg), scans, bucketed scatter, fine scatter
    bucket_hist_kernel<<<B_SCAT, 256, 0, stream>>>(dst, deg, bhist, e);
    int nb = (n + SCHUNK - 1) / SCHUNK;
    scan_part_kernel<<<nb, 256, 0, stream>>>(deg, partials, n);
    scan_top_kernel<<<1, 1024, 0, stream>>>(partials, nb);
    scan_final_kernel<<<nb, SCHUNK, 0, stream>>>(deg, partials, off, n, e);
    bucket_scan_kernel<<<1, 1024, 0, stream>>>(bhist, bscan, NBUCK * B_SCAT);
    bucket_scatter_kernel<<<B_SCAT, 256, 0, stream>>>(src, dst, edge_type, bscan, rec, e);
    fine_scatter_kernel<<<NBUCK, 256, 0, stream>>>(rec, bscan, off, packed, n, e);

    int tblocks = (n + MT - 1) / MT;

    // layer 0
    transform_mfma_kernel<DIN, false><<<tblocks, 256, 0, stream>>>(
        x, nullptr, nullptr, nullptr, wt0h, wt0l, aq[0], ak[0], y, qv, kv, n);
    attn_kernel<<<2048, 256, 0, stream>>>(off, packed, y, qv, kv, bb[0], hpre, stats + 0 * 64, n);

    // layer 1
    transform_mfma_kernel<DH, true><<<tblocks, 256, 0, stream>>>(
        hpre, stats + 0 * 64, gm[0], be[0], wt1h, wt1l, aq[1], ak[1], y, qv, kv, n);
    attn_kernel<<<2048, 256, 0, stream>>>(off, packed, y, qv, kv, bb[1], hpre, stats + 1 * 64, n);

    // layer 2
    transform_mfma_kernel<DH, true><<<tblocks, 256, 0, stream>>>(
        hpre, stats + 1 * 64, gm[1], be[1], wt2h, wt2l, aq[2], ak[2], y, qv, kv, n);
    attn_kernel<<<2048, 256, 0, stream>>>(off, packed, y, qv, kv, bb[2], hpre, stats + 2 * 64, n);

    // final BN + MLP head
    mlp_kernel<<<((size_t)n * 32 + 255) / 256, 256, 0, stream>>>(
        hpre, stats + 2 * 64, gm[2], be[2], mw1, mb1, mw2, mb2, out, n);
}

// Round 6
// 489.762 us; speedup vs baseline: 1.2451x; 1.2451x over previous
//
#include <hip/hip_runtime.h>
#include <math.h>

#define N_NODES 100000
#define N_EDGES 1600000
#define DIN 128
#define DH 32
#define NEG_SLOPE 0.2f
#define BN_EPS 1e-5f
#define MT 64        // nodes per transform block
#define BSHIFT 9     // 512 nodes per bucket
#define NBUCK 196    // ceil(N_NODES / 512)
#define B_SCAT 256   // blocks for bucket hist/scatter
#define CPB ((N_EDGES + B_SCAT - 1) / B_SCAT)

typedef __attribute__((ext_vector_type(8))) short short8;
typedef __attribute__((ext_vector_type(4))) float f32x4;

__device__ __forceinline__ unsigned short f2bf(float f) {
    unsigned int u = __float_as_uint(f);
    u = (u + 0x7FFFu + ((u >> 16) & 1u)) >> 16;
    return (unsigned short)u;
}
__device__ __forceinline__ float bf2f(unsigned short h) {
    return __uint_as_float((unsigned int)h << 16);
}

// ---------------- CSR build: two-level counting sort ----------------
// Phase 1: per-block bucket histograms

__global__ __launch_bounds__(256) void bucket_hist_kernel(
    const int* __restrict__ dst, int* __restrict__ bh, int e) {
    __shared__ int lh[NBUCK];
    for (int j = threadIdx.x; j < NBUCK; j += 256) lh[j] = 0;
    __syncthreads();
    int b = blockIdx.x;
    int lo = b * CPB, hi = min(lo + CPB, e);
    for (int i = lo + threadIdx.x; i < hi; i += 256)
        atomicAdd(&lh[dst[i] >> BSHIFT], 1);
    __syncthreads();
    for (int j = threadIdx.x; j < NBUCK; j += 256) bh[j * B_SCAT + b] = lh[j];
}

// Phase 2: exclusive scan over NBUCK*B_SCAT counters (bucket-major)
__global__ __launch_bounds__(1024) void bucket_scan_kernel(
    const int* __restrict__ bh, int* __restrict__ bs, int total) {
    __shared__ int part[1024];
    int t = threadIdx.x;
    int chunk = (total + 1023) >> 10;
    int lo = t * chunk, hi = min(lo + chunk, total);
    int s = 0;
    for (int i = lo; i < hi; ++i) s += bh[i];
    part[t] = s;
    __syncthreads();
    for (int d = 1; d < 1024; d <<= 1) {
        int v = (t >= d) ? part[t - d] : 0;
        __syncthreads();
        part[t] += v;
        __syncthreads();
    }
    int run = t ? part[t - 1] : 0;
    for (int i = lo; i < hi; ++i) { int v = bh[i]; bs[i] = run; run += v; }
}

// Phase 3: bucketed scatter; each (block,bucket) region is private+contiguous
__global__ __launch_bounds__(256) void bucket_scatter_kernel(
    const int* __restrict__ src, const int* __restrict__ dst, const int* __restrict__ et,
    const int* __restrict__ bs, int2* __restrict__ rec, int e) {
    __shared__ int cur[NBUCK];
    int b = blockIdx.x;
    for (int j = threadIdx.x; j < NBUCK; j += 256) cur[j] = bs[j * B_SCAT + b];
    __syncthreads();
    int lo = b * CPB, hi = min(lo + CPB, e);
    for (int i = lo + threadIdx.x; i < hi; i += 256) {
        int d = dst[i];
        int pos = atomicAdd(&cur[d >> BSHIFT], 1);
        rec[pos] = make_int2(d, src[i] | (et[i] << 30));
    }
}

// Phase 4: fine scatter within each bucket; also derives per-node degrees,
// block-scans them, and writes the CSR off[] — no separate deg/scan kernels.
__global__ __launch_bounds__(256) void fine_scatter_kernel(
    const int2* __restrict__ rec, const int* __restrict__ bs,
    int* __restrict__ off, int* __restrict__ packed, int n, int e) {
    __shared__ int ldeg[1 << BSHIFT];
    __shared__ int lpos[1 << BSHIFT];
    int k = blockIdx.x, t = threadIdx.x;
    int nb0 = k << BSHIFT;
    ldeg[t] = 0;
    ldeg[t + 256] = 0;
    __syncthreads();
    int start = bs[k * B_SCAT];
    int end = (k + 1 < NBUCK) ? bs[(k + 1) * B_SCAT] : e;
    for (int i = start + t; i < end; i += 256)
        atomicAdd(&ldeg[rec[i].x - nb0], 1);
    __syncthreads();
    lpos[t] = ldeg[t];
    lpos[t + 256] = ldeg[t + 256];
    __syncthreads();
    for (int d = 1; d < (1 << BSHIFT); d <<= 1) {
        int v0 = (t >= d) ? lpos[t - d] : 0;
        int v1 = (t + 256 >= d) ? lpos[t + 256 - d] : 0;
        __syncthreads();
        lpos[t] += v0;
        lpos[t + 256] += v1;
        __syncthreads();
    }
    int e0 = lpos[t] - ldeg[t];          // exclusive
    int e1 = lpos[t + 256] - ldeg[t + 256];
    __syncthreads();
    lpos[t] = start + e0;
    lpos[t + 256] = start + e1;
    int node0 = nb0 + t, node1 = nb0 + t + 256;
    if (node0 < n) off[node0] = start + e0;
    if (node1 < n) off[node1] = start + e1;
    if (k == 0 && t == 0) off[n] = e;
    __syncthreads();
    for (int i = start + t; i < end; i += 256) {
        int2 r = rec[i];
        int pos = atomicAdd(&lpos[r.x - nb0], 1);
        packed[pos] = r.y;
    }
}

// -------- weight conversion: Wt[col][k] = split-bf16 of w[r][k][c], col=r*32+c ----

__global__ void wconv_kernel(const float* __restrict__ w,
                             unsigned short* __restrict__ wt_hi,
                             unsigned short* __restrict__ wt_lo, int K) {
    int i = blockIdx.x * blockDim.x + threadIdx.x;
    if (i >= 64 * K) return;
    int col = i / K, k = i % K;
    int r = col >> 5, c = col & 31;
    float v = w[(r * K + k) * DH + c];
    unsigned short h = f2bf(v);
    wt_hi[i] = h;
    wt_lo[i] = f2bf(v - bf2f(h));
}

// ---------------- MFMA transform: y[node][64] = X[node][K] @ Wmat[K][64] ----------
// Split-bf16 (hi+lo) on both operands: acc = aH*bH + aH*bL + aL*bH  (~fp32 accuracy).
// y is stored in bf16 (V side of attention); q/k row-dots stay fp32-exact.

template<int K, bool FUSE_BN>
__global__ __launch_bounds__(256) void transform_mfma_kernel(
    const float* __restrict__ xin, const float* __restrict__ stats,
    const float* __restrict__ gamma, const float* __restrict__ beta,
    const unsigned short* __restrict__ WtHi, const unsigned short* __restrict__ WtLo,
    const float* __restrict__ Qw, const float* __restrict__ Kw,
    unsigned short* __restrict__ yb, float* __restrict__ qv, float* __restrict__ kv, int n) {
    constexpr int LDK = K + 8;          // +8 elems (16B) pad -> bank spread
    constexpr int KT = K / 32;
    __shared__ unsigned short xs_hi[MT * LDK];
    __shared__ unsigned short xs_lo[MT * LDK];
    __shared__ float scs[DH], shs[DH];
    int tid = threadIdx.x;
    int base = blockIdx.x * MT;

    if (FUSE_BN) {
        if (tid < DH) {
            float mu = stats[tid] * (1.f / N_NODES);
            float var = stats[DH + tid] * (1.f / N_NODES) - mu * mu;
            float inv = rsqrtf(var + BN_EPS);
            float sc = gamma[tid] * inv;
            scs[tid] = sc;
            shs[tid] = beta[tid] - mu * sc;
        }
        __syncthreads();
    }

    // stage X tile (fp32 -> hi/lo bf16) into LDS
    constexpr int CH = K / 4;
    for (int c = tid; c < MT * CH; c += 256) {
        int row = c / CH, c4 = c % CH;
        int node = base + row;
        float4 v = make_float4(0.f, 0.f, 0.f, 0.f);
        if (node < n) v = ((const float4*)(xin + (size_t)node * K))[c4];
        if (FUSE_BN) {
            int c0 = c4 * 4;
            v.x = v.x * scs[c0 + 0] + shs[c0 + 0];
            v.y = v.y * scs[c0 + 1] + shs[c0 + 1];
            v.z = v.z * scs[c0 + 2] + shs[c0 + 2];
            v.w = v.w * scs[c0 + 3] + shs[c0 + 3];
        }
        ushort4 hb = make_ushort4(f2bf(v.x), f2bf(v.y), f2bf(v.z), f2bf(v.w));
        ushort4 lb = make_ushort4(f2bf(v.x - bf2f(hb.x)), f2bf(v.y - bf2f(hb.y)),
                                  f2bf(v.z - bf2f(hb.z)), f2bf(v.w - bf2f(hb.w)));
        *(ushort4*)(&xs_hi[row * LDK + c4 * 4]) = hb;
        *(ushort4*)(&xs_lo[row * LDK + c4 * 4]) = lb;
    }
    __syncthreads();

    int lane = tid & 63;
    int wave = tid >> 6;                 // 4 waves x 16 rows
    int r16 = lane & 15, g = lane >> 4;  // frag coords
    int wrow = wave * 16;

    f32x4 acc[4];
#pragma unroll
    for (int nt = 0; nt < 4; ++nt) acc[nt] = f32x4{0.f, 0.f, 0.f, 0.f};

#pragma unroll
    for (int kt = 0; kt < KT; ++kt) {
        short8 a_hi = *(const short8*)(&xs_hi[(wrow + r16) * LDK + kt * 32 + g * 8]);
        short8 a_lo = *(const short8*)(&xs_lo[(wrow + r16) * LDK + kt * 32 + g * 8]);
#pragma unroll
        for (int nt = 0; nt < 4; ++nt) {
            const size_t bo = (size_t)(nt * 16 + r16) * K + kt * 32 + g * 8;
            short8 b_hi = *(const short8*)(WtHi + bo);
            short8 b_lo = *(const short8*)(WtLo + bo);
            acc[nt] = __builtin_amdgcn_mfma_f32_16x16x32_bf16(a_hi, b_hi, acc[nt], 0, 0, 0);
            acc[nt] = __builtin_amdgcn_mfma_f32_16x16x32_bf16(a_hi, b_lo, acc[nt], 0, 0, 0);
            acc[nt] = __builtin_amdgcn_mfma_f32_16x16x32_bf16(a_lo, b_hi, acc[nt], 0, 0, 0);
        }
    }

    // epilogue: bf16 y stores + fused fp32 q/k row-dots
    float qp[2][4] = {{0.f, 0.f, 0.f, 0.f}, {0.f, 0.f, 0.f, 0.f}};
    float kp[2][4] = {{0.f, 0.f, 0.f, 0.f}, {0.f, 0.f, 0.f, 0.f}};
#pragma unroll
    for (int nt = 0; nt < 4; ++nt) {
        int col = nt * 16 + r16;
        int rr = col >> 5, cc = col & 31;
        float qw = Qw[rr * DH + cc], kw = Kw[rr * DH + cc];
#pragma unroll
        for (int j = 0; j < 4; ++j) {
            float v = acc[nt][j];
            qp[rr][j] += v * qw;
            kp[rr][j] += v * kw;
            int node = base + wrow + g * 4 + j;
            if (node < n) yb[(size_t)node * 64 + col] = f2bf(v);
        }
    }
#pragma unroll
    for (int j = 0; j < 4; ++j) {
#pragma unroll
        for (int rr = 0; rr < 2; ++rr) {
            float q = qp[rr][j], k = kp[rr][j];
            for (int d = 8; d; d >>= 1) {
                q += __shfl_xor(q, d, 16);
                k += __shfl_xor(k, d, 16);
            }
            if (r16 == 0) {
                int node = base + wrow + g * 4 + j;
                if (node < n) {
                    qv[node * 2 + rr] = q;
                    kv[node * 2 + rr] = k;
                }
            }
        }
    }
}

// ---------------- fused attention + aggregate + relu + BN stats ----------------
// Single sweep; y gathered as bf16 (64B row = one cache line), weights fp32.

__global__ __launch_bounds__(256) void attn_kernel(
    const int* __restrict__ off, const int* __restrict__ packed,
    const unsigned short* __restrict__ y, const float* __restrict__ qv,
    const float* __restrict__ kv, const float* __restrict__ bias,
    float* __restrict__ hpre, float* __restrict__ stats, int n) {
    __shared__ float ssum[DH], ssq[DH];
    if (threadIdx.x < DH) { ssum[threadIdx.x] = 0.f; ssq[threadIdx.x] = 0.f; }
    __syncthreads();
    int lane = threadIdx.x & 31;
    int sub = threadIdx.x >> 5;
    int spb = blockDim.x >> 5;
    float rsum = 0.f, rsq = 0.f;
    for (int node = blockIdx.x * spb + sub; node < n; node += gridDim.x * spb) {
        int lo = off[node], hi = off[node + 1];
        float q0 = qv[node * 2], q1 = qv[node * 2 + 1];
        float acc0 = 0.f, acc1 = 0.f, wsum = 0.f;
        for (int base = lo; base < hi; base += 32) {
            int i = base + lane;
            float w = 0.f;
            int row = 0;
            if (i < hi) {
                int p = packed[i];
                int s = p & 0x3FFFFFFF, r = p >> 30;
                float ev = (r ? q1 : q0) + kv[s * 2 + r];
                ev = ev > 0.f ? ev : NEG_SLOPE * ev;
                w = __expf(ev - 8.f);
                row = s * 64 + r * 32;
            }
            wsum += w;
            int cnt = min(32, hi - base);
            int j = 0;
            for (; j + 2 <= cnt; j += 2) {
                float w0 = __shfl(w, j, 32), w1 = __shfl(w, j + 1, 32);
                int r0 = __shfl(row, j, 32), r1 = __shfl(row, j + 1, 32);
                acc0 += w0 * bf2f(y[r0 + lane]);
                acc1 += w1 * bf2f(y[r1 + lane]);
            }
            if (j < cnt) {
                float w0 = __shfl(w, j, 32);
                int r0 = __shfl(row, j, 32);
                acc0 += w0 * bf2f(y[r0 + lane]);
            }
        }
        for (int d = 16; d; d >>= 1) wsum += __shfl_xor(wsum, d, 32);
        float h = fmaxf((acc0 + acc1) / (wsum + 1e-16f) + bias[lane], 0.f);
        hpre[(size_t)node * DH + lane] = h;
        rsum += h;
        rsq += h * h;
    }
    atomicAdd(&ssum[lane], rsum);
    atomicAdd(&ssq[lane], rsq);
    __syncthreads();
    if (threadIdx.x < DH) {
        atomicAdd(&stats[threadIdx.x], ssum[threadIdx.x]);
        atomicAdd(&stats[DH + threadIdx.x], ssq[threadIdx.x]);
    }
}

// ---------------- final BN + MLP head ----------------

__global__ __launch_bounds__(256) void mlp_kernel(
    const float* __restrict__ hpre, const float* __restrict__ stats,
    const float* __restrict__ gamma, const float* __restrict__ beta,
    const float* __restrict__ mw1, const float* __restrict__ mb1,
    const float* __restrict__ mw2, const float* __restrict__ mb2,
    float* __restrict__ out, int n) {
    int g = (blockIdx.x * blockDim.x + threadIdx.x) >> 5;
    int lane = threadIdx.x & 31;
    if (g >= n) return;
    float mu = stats[lane] * (1.f / N_NODES);
    float var = stats[DH + lane] * (1.f / N_NODES) - mu * mu;
    float inv = rsqrtf(var + BN_EPS);
    float h = gamma[lane] * (hpre[(size_t)g * DH + lane] - mu) * inv + beta[lane];
    float a = mb1[lane];
#pragma unroll
    for (int f = 0; f < DH; ++f) a += __shfl(h, f, 32) * mw1[f * DH + lane];
    float s = 1.f / (1.f + __expf(-a));
    float o0 = s * mw2[lane * 2 + 0];
    float o1 = s * mw2[lane * 2 + 1];
    for (int d = 16; d; d >>= 1) {
        o0 += __shfl_xor(o0, d, 32);
        o1 += __shfl_xor(o1, d, 32);
    }
    if (lane == 0) {
        out[(size_t)g * 2 + 0] = o0 + mb2[0];
        out[(size_t)g * 2 + 1] = o1 + mb2[1];
    }
}

// ---------------- launch ----------------

extern "C" void kernel_launch(void* const* d_in, const int* in_sizes, int n_in,
                              void* d_out, int out_size, void* d_ws, size_t ws_size,
                              hipStream_t stream) {
    const float* x = (const float*)d_in[0];
    const int* edge_index = (const int*)d_in[1];
    const int* edge_type = (const int*)d_in[2];
    const float* w[3]  = {(const float*)d_in[3],  (const float*)d_in[9],  (const float*)d_in[15]};
    const float* aq[3] = {(const float*)d_in[4],  (const float*)d_in[10], (const float*)d_in[16]};
    const float* ak[3] = {(const float*)d_in[5],  (const float*)d_in[11], (const float*)d_in[17]};
    const float* bb[3] = {(const float*)d_in[6],  (const float*)d_in[12], (const float*)d_in[18]};
    const float* gm[3] = {(const float*)d_in[7],  (const float*)d_in[13], (const float*)d_in[19]};
    const float* be[3] = {(const float*)d_in[8],  (const float*)d_in[14], (const float*)d_in[20]};
    const float* mw1 = (const float*)d_in[21];
    const float* mb1 = (const float*)d_in[22];
    const float* mw2 = (const float*)d_in[23];
    const float* mb2 = (const float*)d_in[24];
    float* out = (float*)d_out;

    const int n = N_NODES, e = N_EDGES;
    char* ws = (char*)d_ws;
    auto alloc = [&](size_t bytes) {
        char* p = ws;
        ws += (bytes + 255) & ~(size_t)255;
        return p;
    };
    int* off      = (int*)alloc((size_t)(n + 1) * 4);
    int* bhist    = (int*)alloc((size_t)NBUCK * B_SCAT * 4);
    int* bscan    = (int*)alloc((size_t)NBUCK * B_SCAT * 4);
    int2* rec     = (int2*)alloc((size_t)e * 8);
    int* packed   = (int*)alloc((size_t)e * 4);
    unsigned short* yb = (unsigned short*)alloc((size_t)n * 2 * DH * 2);
    float* qv     = (float*)alloc((size_t)n * 2 * 4);
    float* kv     = (float*)alloc((size_t)n * 2 * 4);
    float* hpre   = (float*)alloc((size_t)n * DH * 4);
    float* stats  = (float*)alloc(3 * 2 * DH * 4);
    unsigned short* wt0h = (unsigned short*)alloc((size_t)64 * DIN * 2);
    unsigned short* wt0l = (unsigned short*)alloc((size_t)64 * DIN * 2);
    unsigned short* wt1h = (unsigned short*)alloc((size_t)64 * DH * 2);
    unsigned short* wt1l = (unsigned short*)alloc((size_t)64 * DH * 2);
    unsigned short* wt2h = (unsigned short*)alloc((size_t)64 * DH * 2);
    unsigned short* wt2l = (unsigned short*)alloc((size_t)64 * DH * 2);

    hipMemsetAsync(stats, 0, 3 * 2 * DH * 4, stream);

    const int* src = edge_index;
    const int* dst = edge_index + e;

    wconv_kernel<<<(64 * DIN + 255) / 256, 256, 0, stream>>>(w[0], wt0h, wt0l, DIN);
    wconv_kernel<<<(64 * DH + 255) / 256, 256, 0, stream>>>(w[1], wt1h, wt1l, DH);
    wconv_kernel<<<(64 * DH + 255) / 256, 256, 0, stream>>>(w[2], wt2h, wt2l, DH);

    // CSR build: bucket hist, bucket scan, bucketed scatter, fine scatter(+off)
    bucket_hist_kernel<<<B_SCAT, 256, 0, stream>>>(dst, bhist, e);
    bucket_scan_kernel<<<1, 1024, 0, stream>>>(bhist, bscan, NBUCK * B_SCAT);
    bucket_scatter_kernel<<<B_SCAT, 256, 0, stream>>>(src, dst, edge_type, bscan, rec, e);
    fine_scatter_kernel<<<NBUCK, 256, 0, stream>>>(rec, bscan, off, packed, n, e);

    int tblocks = (n + MT - 1) / MT;

    // layer 0
    transform_mfma_kernel<DIN, false><<<tblocks, 256, 0, stream>>>(
        x, nullptr, nullptr, nullptr, wt0h, wt0l, aq[0], ak[0], yb, qv, kv, n);
    attn_kernel<<<2048, 256, 0, stream>>>(off, packed, yb, qv, kv, bb[0], hpre, stats + 0 * 64, n);

    // layer 1
    transform_mfma_kernel<DH, true><<<tblocks, 256, 0, stream>>>(
        hpre, stats + 0 * 64, gm[0], be[0], wt1h, wt1l, aq[1], ak[1], yb, qv, kv, n);
    attn_kernel<<<2048, 256, 0, stream>>>(off, packed, yb, qv, kv, bb[1], hpre, stats + 1 * 64, n);

    // layer 2
    transform_mfma_kernel<DH, true><<<tblocks, 256, 0, stream>>>(
        hpre, stats + 1 * 64, gm[1], be[1], wt2h, wt2l, aq[2], ak[2], yb, qv, kv, n);
    attn_kernel<<<2048, 256, 0, stream>>>(off, packed, yb, qv, kv, bb[2], hpre, stats + 2 * 64, n);

    // final BN + MLP head
    mlp_kernel<<<((size_t)n * 32 + 255) / 256, 256, 0, stream>>>(
        hpre, stats + 2 * 64, gm[2], be[2], mw1, mb1, mw2, mb2, out, n);
}

// Round 7
// 475.982 us; speedup vs baseline: 1.2811x; 1.0290x over previous
//
#include <hip/hip_runtime.h>
#include <math.h>

#define N_NODES 100000
#define N_EDGES 1600000
#define DIN 128
#define DH 32
#define NEG_SLOPE 0.2f
#define BN_EPS 1e-5f
#define MT 64        // nodes per transform block
#define BSHIFT 9     // 512 nodes per bucket
#define NBUCK 196    // ceil(N_NODES / 512)
#define B_SCAT 256   // blocks for bucket hist/scatter
#define CPB ((N_EDGES + B_SCAT - 1) / B_SCAT)

typedef __attribute__((ext_vector_type(8))) short short8;
typedef __attribute__((ext_vector_type(4))) float f32x4;

__device__ __forceinline__ unsigned short f2bf(float f) {
    unsigned int u = __float_as_uint(f);
    u = (u + 0x7FFFu + ((u >> 16) & 1u)) >> 16;
    return (unsigned short)u;
}
__device__ __forceinline__ float bf2f(unsigned short h) {
    return __uint_as_float((unsigned int)h << 16);
}

// ---------------- CSR build: two-level counting sort ----------------
// Phase 1: per-block bucket histograms

__global__ __launch_bounds__(256) void bucket_hist_kernel(
    const int* __restrict__ dst, int* __restrict__ bh, int e) {
    __shared__ int lh[NBUCK];
    for (int j = threadIdx.x; j < NBUCK; j += 256) lh[j] = 0;
    __syncthreads();
    int b = blockIdx.x;
    int lo = b * CPB, hi = min(lo + CPB, e);
    for (int i = lo + threadIdx.x; i < hi; i += 256)
        atomicAdd(&lh[dst[i] >> BSHIFT], 1);
    __syncthreads();
    for (int j = threadIdx.x; j < NBUCK; j += 256) bh[j * B_SCAT + b] = lh[j];
}

// Phase 2: exclusive scan over NBUCK*B_SCAT counters (bucket-major)
__global__ __launch_bounds__(1024) void bucket_scan_kernel(
    const int* __restrict__ bh, int* __restrict__ bs, int total) {
    __shared__ int part[1024];
    int t = threadIdx.x;
    int chunk = (total + 1023) >> 10;
    int lo = t * chunk, hi = min(lo + chunk, total);
    int s = 0;
    for (int i = lo; i < hi; ++i) s += bh[i];
    part[t] = s;
    __syncthreads();
    for (int d = 1; d < 1024; d <<= 1) {
        int v = (t >= d) ? part[t - d] : 0;
        __syncthreads();
        part[t] += v;
        __syncthreads();
    }
    int run = t ? part[t - 1] : 0;
    for (int i = lo; i < hi; ++i) { int v = bh[i]; bs[i] = run; run += v; }
}

// Phase 3: bucketed scatter; each (block,bucket) region is private+contiguous
__global__ __launch_bounds__(256) void bucket_scatter_kernel(
    const int* __restrict__ src, const int* __restrict__ dst, const int* __restrict__ et,
    const int* __restrict__ bs, int2* __restrict__ rec, int e) {
    __shared__ int cur[NBUCK];
    int b = blockIdx.x;
    for (int j = threadIdx.x; j < NBUCK; j += 256) cur[j] = bs[j * B_SCAT + b];
    __syncthreads();
    int lo = b * CPB, hi = min(lo + CPB, e);
    for (int i = lo + threadIdx.x; i < hi; i += 256) {
        int d = dst[i];
        int pos = atomicAdd(&cur[d >> BSHIFT], 1);
        rec[pos] = make_int2(d, src[i] | (et[i] << 30));
    }
}

// Phase 4: fine scatter within each bucket; also derives per-node degrees,
// block-scans them, and writes the CSR off[] — no separate deg/scan kernels.
__global__ __launch_bounds__(256) void fine_scatter_kernel(
    const int2* __restrict__ rec, const int* __restrict__ bs,
    int* __restrict__ off, int* __restrict__ packed, int n, int e) {
    __shared__ int ldeg[1 << BSHIFT];
    __shared__ int lpos[1 << BSHIFT];
    int k = blockIdx.x, t = threadIdx.x;
    int nb0 = k << BSHIFT;
    ldeg[t] = 0;
    ldeg[t + 256] = 0;
    __syncthreads();
    int start = bs[k * B_SCAT];
    int end = (k + 1 < NBUCK) ? bs[(k + 1) * B_SCAT] : e;
    for (int i = start + t; i < end; i += 256)
        atomicAdd(&ldeg[rec[i].x - nb0], 1);
    __syncthreads();
    lpos[t] = ldeg[t];
    lpos[t + 256] = ldeg[t + 256];
    __syncthreads();
    for (int d = 1; d < (1 << BSHIFT); d <<= 1) {
        int v0 = (t >= d) ? lpos[t - d] : 0;
        int v1 = (t + 256 >= d) ? lpos[t + 256 - d] : 0;
        __syncthreads();
        lpos[t] += v0;
        lpos[t + 256] += v1;
        __syncthreads();
    }
    int e0 = lpos[t] - ldeg[t];          // exclusive
    int e1 = lpos[t + 256] - ldeg[t + 256];
    __syncthreads();
    lpos[t] = start + e0;
    lpos[t + 256] = start + e1;
    int node0 = nb0 + t, node1 = nb0 + t + 256;
    if (node0 < n) off[node0] = start + e0;
    if (node1 < n) off[node1] = start + e1;
    if (k == 0 && t == 0) off[n] = e;
    __syncthreads();
    for (int i = start + t; i < end; i += 256) {
        int2 r = rec[i];
        int pos = atomicAdd(&lpos[r.x - nb0], 1);
        packed[pos] = r.y;
    }
}

// -------- weight conversion: Wt[col][k] = split-bf16 of w[r][k][c], col=r*32+c ----

__global__ void wconv_kernel(const float* __restrict__ w,
                             unsigned short* __restrict__ wt_hi,
                             unsigned short* __restrict__ wt_lo, int K) {
    int i = blockIdx.x * blockDim.x + threadIdx.x;
    if (i >= 64 * K) return;
    int col = i / K, k = i % K;
    int r = col >> 5, c = col & 31;
    float v = w[(r * K + k) * DH + c];
    unsigned short h = f2bf(v);
    wt_hi[i] = h;
    wt_lo[i] = f2bf(v - bf2f(h));
}

// ---------------- MFMA transform: y[node][64] = X[node][K] @ Wmat[K][64] ----------
// Split-bf16 (hi+lo) on both operands: acc = aH*bH + aH*bL + aL*bH  (~fp32 accuracy).
// y is stored in bf16 (V side of attention); q/k row-dots stay fp32-exact.

template<int K, bool FUSE_BN>
__global__ __launch_bounds__(256) void transform_mfma_kernel(
    const float* __restrict__ xin, const float* __restrict__ stats,
    const float* __restrict__ gamma, const float* __restrict__ beta,
    const unsigned short* __restrict__ WtHi, const unsigned short* __restrict__ WtLo,
    const float* __restrict__ Qw, const float* __restrict__ Kw,
    unsigned short* __restrict__ yb, float* __restrict__ qv, float* __restrict__ kv, int n) {
    constexpr int LDK = K + 8;          // +8 elems (16B) pad -> bank spread
    constexpr int KT = K / 32;
    __shared__ unsigned short xs_hi[MT * LDK];
    __shared__ unsigned short xs_lo[MT * LDK];
    __shared__ float scs[DH], shs[DH];
    int tid = threadIdx.x;
    int base = blockIdx.x * MT;

    if (FUSE_BN) {
        if (tid < DH) {
            float mu = stats[tid] * (1.f / N_NODES);
            float var = stats[DH + tid] * (1.f / N_NODES) - mu * mu;
            float inv = rsqrtf(var + BN_EPS);
            float sc = gamma[tid] * inv;
            scs[tid] = sc;
            shs[tid] = beta[tid] - mu * sc;
        }
        __syncthreads();
    }

    // stage X tile (fp32 -> hi/lo bf16) into LDS
    constexpr int CH = K / 4;
    for (int c = tid; c < MT * CH; c += 256) {
        int row = c / CH, c4 = c % CH;
        int node = base + row;
        float4 v = make_float4(0.f, 0.f, 0.f, 0.f);
        if (node < n) v = ((const float4*)(xin + (size_t)node * K))[c4];
        if (FUSE_BN) {
            int c0 = c4 * 4;
            v.x = v.x * scs[c0 + 0] + shs[c0 + 0];
            v.y = v.y * scs[c0 + 1] + shs[c0 + 1];
            v.z = v.z * scs[c0 + 2] + shs[c0 + 2];
            v.w = v.w * scs[c0 + 3] + shs[c0 + 3];
        }
        ushort4 hb = make_ushort4(f2bf(v.x), f2bf(v.y), f2bf(v.z), f2bf(v.w));
        ushort4 lb = make_ushort4(f2bf(v.x - bf2f(hb.x)), f2bf(v.y - bf2f(hb.y)),
                                  f2bf(v.z - bf2f(hb.z)), f2bf(v.w - bf2f(hb.w)));
        *(ushort4*)(&xs_hi[row * LDK + c4 * 4]) = hb;
        *(ushort4*)(&xs_lo[row * LDK + c4 * 4]) = lb;
    }
    __syncthreads();

    int lane = tid & 63;
    int wave = tid >> 6;                 // 4 waves x 16 rows
    int r16 = lane & 15, g = lane >> 4;  // frag coords
    int wrow = wave * 16;

    f32x4 acc[4];
#pragma unroll
    for (int nt = 0; nt < 4; ++nt) acc[nt] = f32x4{0.f, 0.f, 0.f, 0.f};

#pragma unroll
    for (int kt = 0; kt < KT; ++kt) {
        short8 a_hi = *(const short8*)(&xs_hi[(wrow + r16) * LDK + kt * 32 + g * 8]);
        short8 a_lo = *(const short8*)(&xs_lo[(wrow + r16) * LDK + kt * 32 + g * 8]);
#pragma unroll
        for (int nt = 0; nt < 4; ++nt) {
            const size_t bo = (size_t)(nt * 16 + r16) * K + kt * 32 + g * 8;
            short8 b_hi = *(const short8*)(WtHi + bo);
            short8 b_lo = *(const short8*)(WtLo + bo);
            acc[nt] = __builtin_amdgcn_mfma_f32_16x16x32_bf16(a_hi, b_hi, acc[nt], 0, 0, 0);
            acc[nt] = __builtin_amdgcn_mfma_f32_16x16x32_bf16(a_hi, b_lo, acc[nt], 0, 0, 0);
            acc[nt] = __builtin_amdgcn_mfma_f32_16x16x32_bf16(a_lo, b_hi, acc[nt], 0, 0, 0);
        }
    }

    // epilogue: bf16 y stores + fused fp32 q/k row-dots
    float qp[2][4] = {{0.f, 0.f, 0.f, 0.f}, {0.f, 0.f, 0.f, 0.f}};
    float kp[2][4] = {{0.f, 0.f, 0.f, 0.f}, {0.f, 0.f, 0.f, 0.f}};
#pragma unroll
    for (int nt = 0; nt < 4; ++nt) {
        int col = nt * 16 + r16;
        int rr = col >> 5, cc = col & 31;
        float qw = Qw[rr * DH + cc], kw = Kw[rr * DH + cc];
#pragma unroll
        for (int j = 0; j < 4; ++j) {
            float v = acc[nt][j];
            qp[rr][j] += v * qw;
            kp[rr][j] += v * kw;
            int node = base + wrow + g * 4 + j;
            if (node < n) yb[(size_t)node * 64 + col] = f2bf(v);
        }
    }
#pragma unroll
    for (int j = 0; j < 4; ++j) {
#pragma unroll
        for (int rr = 0; rr < 2; ++rr) {
            float q = qp[rr][j], k = kp[rr][j];
            for (int d = 8; d; d >>= 1) {
                q += __shfl_xor(q, d, 16);
                k += __shfl_xor(k, d, 16);
            }
            if (r16 == 0) {
                int node = base + wrow + g * 4 + j;
                if (node < n) {
                    qv[node * 2 + rr] = q;
                    kv[node * 2 + rr] = k;
                }
            }
        }
    }
}

// ---------------- fused attention + aggregate + relu + BN stats ----------------
// Single sweep; y gathered as bf16 (64B row = one cache line), weights fp32.
// 4-way unrolled gather: 4 independent accumulators keep 4 lines in flight
// per subwave (latency/MLP-bound per round-6 counters).

__global__ __launch_bounds__(256) void attn_kernel(
    const int* __restrict__ off, const int* __restrict__ packed,
    const unsigned short* __restrict__ y, const float* __restrict__ qv,
    const float* __restrict__ kv, const float* __restrict__ bias,
    float* __restrict__ hpre, float* __restrict__ stats, int n) {
    __shared__ float ssum[DH], ssq[DH];
    if (threadIdx.x < DH) { ssum[threadIdx.x] = 0.f; ssq[threadIdx.x] = 0.f; }
    __syncthreads();
    int lane = threadIdx.x & 31;
    int sub = threadIdx.x >> 5;
    int spb = blockDim.x >> 5;
    float rsum = 0.f, rsq = 0.f;
    float bl = bias[lane];
    for (int node = blockIdx.x * spb + sub; node < n; node += gridDim.x * spb) {
        int lo = off[node], hi = off[node + 1];
        float q0 = qv[node * 2], q1 = qv[node * 2 + 1];
        float acc0 = 0.f, acc1 = 0.f, acc2 = 0.f, acc3 = 0.f, wsum = 0.f;
        for (int base = lo; base < hi; base += 32) {
            int i = base + lane;
            float w = 0.f;
            int row = 0;
            if (i < hi) {
                int p = packed[i];
                int s = p & 0x3FFFFFFF, r = p >> 30;
                float ev = (r ? q1 : q0) + kv[s * 2 + r];
                ev = ev > 0.f ? ev : NEG_SLOPE * ev;
                w = __expf(ev - 8.f);
                row = s * 64 + r * 32;
            }
            wsum += w;
            int cnt = min(32, hi - base);
            int j = 0;
            for (; j + 4 <= cnt; j += 4) {
                float w0 = __shfl(w, j, 32),     w1 = __shfl(w, j + 1, 32);
                float w2 = __shfl(w, j + 2, 32), w3 = __shfl(w, j + 3, 32);
                int r0 = __shfl(row, j, 32),     r1 = __shfl(row, j + 1, 32);
                int r2 = __shfl(row, j + 2, 32), r3 = __shfl(row, j + 3, 32);
                acc0 += w0 * bf2f(y[r0 + lane]);
                acc1 += w1 * bf2f(y[r1 + lane]);
                acc2 += w2 * bf2f(y[r2 + lane]);
                acc3 += w3 * bf2f(y[r3 + lane]);
            }
            for (; j < cnt; ++j) {
                float w0 = __shfl(w, j, 32);
                int r0 = __shfl(row, j, 32);
                acc0 += w0 * bf2f(y[r0 + lane]);
            }
        }
        for (int d = 16; d; d >>= 1) wsum += __shfl_xor(wsum, d, 32);
        float h = fmaxf((acc0 + acc1 + acc2 + acc3) / (wsum + 1e-16f) + bl, 0.f);
        hpre[(size_t)node * DH + lane] = h;
        rsum += h;
        rsq += h * h;
    }
    atomicAdd(&ssum[lane], rsum);
    atomicAdd(&ssq[lane], rsq);
    __syncthreads();
    if (threadIdx.x < DH) {
        atomicAdd(&stats[threadIdx.x], ssum[threadIdx.x]);
        atomicAdd(&stats[DH + threadIdx.x], ssq[threadIdx.x]);
    }
}

// ---------------- final BN + MLP head ----------------

__global__ __launch_bounds__(256) void mlp_kernel(
    const float* __restrict__ hpre, const float* __restrict__ stats,
    const float* __restrict__ gamma, const float* __restrict__ beta,
    const float* __restrict__ mw1, const float* __restrict__ mb1,
    const float* __restrict__ mw2, const float* __restrict__ mb2,
    float* __restrict__ out, int n) {
    int g = (blockIdx.x * blockDim.x + threadIdx.x) >> 5;
    int lane = threadIdx.x & 31;
    if (g >= n) return;
    float mu = stats[lane] * (1.f / N_NODES);
    float var = stats[DH + lane] * (1.f / N_NODES) - mu * mu;
    float inv = rsqrtf(var + BN_EPS);
    float h = gamma[lane] * (hpre[(size_t)g * DH + lane] - mu) * inv + beta[lane];
    float a = mb1[lane];
#pragma unroll
    for (int f = 0; f < DH; ++f) a += __shfl(h, f, 32) * mw1[f * DH + lane];
    float s = 1.f / (1.f + __expf(-a));
    float o0 = s * mw2[lane * 2 + 0];
    float o1 = s * mw2[lane * 2 + 1];
    for (int d = 16; d; d >>= 1) {
        o0 += __shfl_xor(o0, d, 32);
        o1 += __shfl_xor(o1, d, 32);
    }
    if (lane == 0) {
        out[(size_t)g * 2 + 0] = o0 + mb2[0];
        out[(size_t)g * 2 + 1] = o1 + mb2[1];
    }
}

// ---------------- launch ----------------

extern "C" void kernel_launch(void* const* d_in, const int* in_sizes, int n_in,
                              void* d_out, int out_size, void* d_ws, size_t ws_size,
                              hipStream_t stream) {
    const float* x = (const float*)d_in[0];
    const int* edge_index = (const int*)d_in[1];
    const int* edge_type = (const int*)d_in[2];
    const float* w[3]  = {(const float*)d_in[3],  (const float*)d_in[9],  (const float*)d_in[15]};
    const float* aq[3] = {(const float*)d_in[4],  (const float*)d_in[10], (const float*)d_in[16]};
    const float* ak[3] = {(const float*)d_in[5],  (const float*)d_in[11], (const float*)d_in[17]};
    const float* bb[3] = {(const float*)d_in[6],  (const float*)d_in[12], (const float*)d_in[18]};
    const float* gm[3] = {(const float*)d_in[7],  (const float*)d_in[13], (const float*)d_in[19]};
    const float* be[3] = {(const float*)d_in[8],  (const float*)d_in[14], (const float*)d_in[20]};
    const float* mw1 = (const float*)d_in[21];
    const float* mb1 = (const float*)d_in[22];
    const float* mw2 = (const float*)d_in[23];
    const float* mb2 = (const float*)d_in[24];
    float* out = (float*)d_out;

    const int n = N_NODES, e = N_EDGES;
    char* ws = (char*)d_ws;
    auto alloc = [&](size_t bytes) {
        char* p = ws;
        ws += (bytes + 255) & ~(size_t)255;
        return p;
    };
    int* off      = (int*)alloc((size_t)(n + 1) * 4);
    int* bhist    = (int*)alloc((size_t)NBUCK * B_SCAT * 4);
    int* bscan    = (int*)alloc((size_t)NBUCK * B_SCAT * 4);
    int2* rec     = (int2*)alloc((size_t)e * 8);
    int* packed   = (int*)alloc((size_t)e * 4);
    unsigned short* yb = (unsigned short*)alloc((size_t)n * 2 * DH * 2);
    float* qv     = (float*)alloc((size_t)n * 2 * 4);
    float* kv     = (float*)alloc((size_t)n * 2 * 4);
    float* hpre   = (float*)alloc((size_t)n * DH * 4);
    float* stats  = (float*)alloc(3 * 2 * DH * 4);
    unsigned short* wt0h = (unsigned short*)alloc((size_t)64 * DIN * 2);
    unsigned short* wt0l = (unsigned short*)alloc((size_t)64 * DIN * 2);
    unsigned short* wt1h = (unsigned short*)alloc((size_t)64 * DH * 2);
    unsigned short* wt1l = (unsigned short*)alloc((size_t)64 * DH * 2);
    unsigned short* wt2h = (unsigned short*)alloc((size_t)64 * DH * 2);
    unsigned short* wt2l = (unsigned short*)alloc((size_t)64 * DH * 2);

    hipMemsetAsync(stats, 0, 3 * 2 * DH * 4, stream);

    const int* src = edge_index;
    const int* dst = edge_index + e;

    wconv_kernel<<<(64 * DIN + 255) / 256, 256, 0, stream>>>(w[0], wt0h, wt0l, DIN);
    wconv_kernel<<<(64 * DH + 255) / 256, 256, 0, stream>>>(w[1], wt1h, wt1l, DH);
    wconv_kernel<<<(64 * DH + 255) / 256, 256, 0, stream>>>(w[2], wt2h, wt2l, DH);

    // CSR build: bucket hist, bucket scan, bucketed scatter, fine scatter(+off)
    bucket_hist_kernel<<<B_SCAT, 256, 0, stream>>>(dst, bhist, e);
    bucket_scan_kernel<<<1, 1024, 0, stream>>>(bhist, bscan, NBUCK * B_SCAT);
    bucket_scatter_kernel<<<B_SCAT, 256, 0, stream>>>(src, dst, edge_type, bscan, rec, e);
    fine_scatter_kernel<<<NBUCK, 256, 0, stream>>>(rec, bscan, off, packed, n, e);

    int tblocks = (n + MT - 1) / MT;

    // layer 0
    transform_mfma_kernel<DIN, false><<<tblocks, 256, 0, stream>>>(
        x, nullptr, nullptr, nullptr, wt0h, wt0l, aq[0], ak[0], yb, qv, kv, n);
    attn_kernel<<<2048, 256, 0, stream>>>(off, packed, yb, qv, kv, bb[0], hpre, stats + 0 * 64, n);

    // layer 1
    transform_mfma_kernel<DH, true><<<tblocks, 256, 0, stream>>>(
        hpre, stats + 0 * 64, gm[0], be[0], wt1h, wt1l, aq[1], ak[1], yb, qv, kv, n);
    attn_kernel<<<2048, 256, 0, stream>>>(off, packed, yb, qv, kv, bb[1], hpre, stats + 1 * 64, n);

    // layer 2
    transform_mfma_kernel<DH, true><<<tblocks, 256, 0, stream>>>(
        hpre, stats + 1 * 64, gm[1], be[1], wt2h, wt2l, aq[2], ak[2], yb, qv, kv, n);
    attn_kernel<<<2048, 256, 0, stream>>>(off, packed, yb, qv, kv, bb[2], hpre, stats + 2 * 64, n);

    // final BN + MLP head
    mlp_kernel<<<((size_t)n * 32 + 255) / 256, 256, 0, stream>>>(
        hpre, stats + 2 * 64, gm[2], be[2], mw1, mb1, mw2, mb2, out, n);
}